// Round 1
// baseline (888.196 us; speedup 1.0000x reference)
//
#include <hip/hip_runtime.h>

#define MAX_VAL 10000.0f

// x: (B=8, C=64, H=512, W=512) float32, row-major.
// Output: erode(3x3 min) on channels in `indices`, copy otherwise.
// One thread per float4 group. Layout of the float4-group index `idx`:
//   w4 = idx & 127        (W/4 = 128 groups per row)
//   h  = (idx >> 7) & 511
//   bc = idx >> 16        (b*64 + c, 512 planes)
// A 256-thread block spans 1024 floats = 2 rows of one plane -> the
// erode/copy branch is block-uniform.
__global__ __launch_bounds__(256) void erode_kernel(
    const float* __restrict__ x,
    const int* __restrict__ indices, int n_idx,
    float* __restrict__ out)
{
    unsigned idx = blockIdx.x * 256u + threadIdx.x;
    unsigned w4 = idx & 127u;
    unsigned h  = (idx >> 7) & 511u;
    unsigned bc = idx >> 16;          // b*64 + c
    unsigned c  = bc & 63u;

    // Block-uniform channel membership: thread 0 scans the (tiny) index list.
    __shared__ int s_flag;
    if (threadIdx.x == 0) {
        int f = 0;
        for (int i = 0; i < n_idx; ++i) f |= (indices[i] == (int)c);
        s_flag = f;
    }
    __syncthreads();

    const float* plane  = x   + (size_t)bc * (512u * 512u);
    float*       oplane = out + (size_t)bc * (512u * 512u);
    unsigned w0 = w4 * 4u;
    const float* src = plane + (size_t)h * 512u + w0;
    float* dst = oplane + (size_t)h * 512u + w0;

    if (!s_flag) {
        // Pass-through channel: vectorized copy.
        *(float4*)dst = *(const float4*)src;
        return;
    }

    // Eroded channel: separable 3x3 min.
    // Vertical min over rows h-1..h+1 for columns w0..w0+3 (vec) and the
    // two halo columns w0-1 / w0+4 (scalar). Out-of-range -> MAX_VAL pad.
    float4 vm = make_float4(MAX_VAL, MAX_VAL, MAX_VAL, MAX_VAL);
    float lm = MAX_VAL, rm = MAX_VAL;
    const bool has_l = (w0 > 0);
    const bool has_r = (w0 + 4u < 512u);

#pragma unroll
    for (int dh = -1; dh <= 1; ++dh) {
        int hh = (int)h + dh;
        if (hh < 0 || hh >= 512) continue;
        const float* row = plane + (size_t)hh * 512u;
        float4 v = *(const float4*)(row + w0);
        vm.x = fminf(vm.x, v.x);
        vm.y = fminf(vm.y, v.y);
        vm.z = fminf(vm.z, v.z);
        vm.w = fminf(vm.w, v.w);
        if (has_l) lm = fminf(lm, row[w0 - 1]);
        if (has_r) rm = fminf(rm, row[w0 + 4]);
    }

    // Horizontal min of the vertical mins, shifted by -1/0/+1.
    float4 r;
    r.x = fminf(fminf(lm,   vm.x), vm.y);
    r.y = fminf(fminf(vm.x, vm.y), vm.z);
    r.z = fminf(fminf(vm.y, vm.z), vm.w);
    r.w = fminf(fminf(vm.z, vm.w), rm);
    *(float4*)dst = r;
}

extern "C" void kernel_launch(void* const* d_in, const int* in_sizes, int n_in,
                              void* d_out, int out_size, void* d_ws, size_t ws_size,
                              hipStream_t stream) {
    const float* x       = (const float*)d_in[0];
    const int*   indices = (const int*)d_in[1];
    // d_in[2] is k (==3), baked into the kernel.
    int n_idx = in_sizes[1];
    float* out = (float*)d_out;

    // Total float4 groups: 8*64*512*512/4 = 33,554,432 -> 131072 blocks of 256.
    unsigned n_groups = 8u * 64u * 512u * 512u / 4u;
    dim3 grid(n_groups / 256u), block(256);
    erode_kernel<<<grid, block, 0, stream>>>(x, indices, n_idx, out);
}